// Round 12
// baseline (2438.766 us; speedup 1.0000x reference)
//
#include <hip/hip_runtime.h>
#include <math.h>

#define B_   64
#define S_   3072
#define DIN  128
#define E_   64
#define H_   256
#define OUT_ 10
#define T_   1024
#define NG   32      // batch groups (2 batches each)
#define GB   2
#define NCH  8       // chunk-WGs per group; WG q owns h-indices [32q,32q+32)
#define NLINES 192   // stamped lines per group per parity: [q][wave][s] 8*8*3
#define LSTRIDE 64   // floats per line slot (256 B) -> spread across LLC banks
#define SLOT 168     // padded k-half slice (168 % 32 = 8 -> bank-disjoint)

// workspace layout (bytes)
#define ACT_BYTES   (B_*E_*T_*4)              // actT[b][e][t] fp32 = 16 MB
#define HBUF_OFF    ACT_BYTES
#define HBUF_BYTES  (NG*2*NLINES*LSTRIDE*4)   // 3 MB (256B-strided 16B lines)
#define HFINAL_OFF  (HBUF_OFF + HBUF_BYTES)
#define HFINAL_BYTES (NG*GB*H_*4)             // 64 KB

typedef float f32x4 __attribute__((ext_vector_type(4)));

// IF-coherent access (cross-XCD safe, fence-free). Proven rounds 2/4/6/7/11.
// NOTE: sc0-only ("XCD-local") exchange hangs — twice confirmed (r3, r10).
__device__ __forceinline__ f32x4 coh_load_f32x4(const float* p) {
  f32x4 r;
  asm volatile("global_load_dwordx4 %0, %1, off sc0 sc1\n\ts_waitcnt vmcnt(0)"
               : "=v"(r) : "v"(p) : "memory");
  return r;
}
__device__ __forceinline__ void coh_store_f32x4(float* p, f32x4 v) {
  asm volatile("global_store_dwordx4 %0, %1, off sc0 sc1" :: "v"(p), "v"(v) : "memory");
}

// step barrier: LDS-drain only (store lanes self-drain their own vmcnt)
__device__ __forceinline__ void step_barrier() {
  asm volatile("s_waitcnt lgkmcnt(0)" ::: "memory");
  __builtin_amdgcn_sched_barrier(0);
  __builtin_amdgcn_s_barrier();
}

__device__ __forceinline__ float fast_sigmoid(float x) {
  return __builtin_amdgcn_rcpf(1.0f + __expf(-x));
}
__device__ __forceinline__ float fast_tanh(float x) {
  return 2.0f * __builtin_amdgcn_rcpf(1.0f + __expf(-2.0f * x)) - 1.0f;
}

// ---------------------------------------------------------------------------
// Conv: normalize rows (L2 over D=128), conv1d k=3 stride=3, +bias, relu.
// ---------------------------------------------------------------------------
__global__ __launch_bounds__(512, 1) void conv_kernel(
    const float* __restrict__ in,     // [B][S][DIN]
    const float* __restrict__ cw,     // [E][DIN][3]
    const float* __restrict__ cb,     // [E]
    float* __restrict__ actT)         // [B][E][T]
{
  extern __shared__ float xs[];                 // 192 rows x 128 f, swizzled
  float4* xs4 = (float4*)xs;
  const int bid = blockIdx.x;
  const int b  = bid >> 4;
  const int tb = bid & 15;
  const int tid = threadIdx.x;

  const float4* gin = (const float4*)(in + (size_t)b*S_*DIN + (size_t)tb*192*DIN);
  #pragma unroll
  for (int i = 0; i < 12; ++i) {
    int f4 = tid + i*512;
    int r = f4 >> 5, dq = f4 & 31;
    xs4[r*32 + (dq ^ (r & 7))] = gin[f4];
  }
  __syncthreads();

  const int wv = tid >> 6, ln = tid & 63;
  for (int rr = 0; rr < 24; ++rr) {
    int r = wv*24 + rr;
    int u = r*32 + ((ln >> 1) ^ (r & 7));
    float2* p = (float2*)((char*)xs + (size_t)u*16 + (size_t)(ln & 1)*8);
    float2 v = *p;
    float s = v.x*v.x + v.y*v.y;
    #pragma unroll
    for (int off = 32; off >= 1; off >>= 1) s += __shfl_xor(s, off);
    float inv = 1.0f / fmaxf(sqrtf(s), 1e-12f);
    v.x *= inv; v.y *= inv;
    *p = v;
  }
  __syncthreads();

  const int eo = __builtin_amdgcn_readfirstlane(wv);
  float acc[8];
  #pragma unroll
  for (int j = 0; j < 8; ++j) acc[j] = cb[eo*8 + j];

  const int r0 = 3*ln, r1 = 3*ln + 1, r2 = 3*ln + 2;
  #pragma unroll 4
  for (int dq = 0; dq < 32; ++dq) {
    float4 x0 = xs4[r0*32 + (dq ^ (r0 & 7))];
    float4 x1 = xs4[r1*32 + (dq ^ (r1 & 7))];
    float4 x2 = xs4[r2*32 + (dq ^ (r2 & 7))];
    #pragma unroll
    for (int j = 0; j < 8; ++j) {
      const float* wp = cw + (size_t)(eo*8 + j)*(DIN*3) + dq*12;  // uniform
      acc[j] += x0.x*wp[0] + x1.x*wp[1] + x2.x*wp[2]
              + x0.y*wp[3] + x1.y*wp[4] + x2.y*wp[5]
              + x0.z*wp[6] + x1.z*wp[7] + x2.z*wp[8]
              + x0.w*wp[9] + x1.w*wp[10] + x2.w*wp[11];
    }
  }

  const int tg = tb*64 + ln;
  #pragma unroll
  for (int j = 0; j < 8; ++j) {
    int e = eo*8 + j;
    actT[(size_t)b*E_*T_ + (size_t)e*T_ + tg] = fmaxf(acc[j], 0.0f);
  }
}

// k index -> (khalf, slot) in the 0-conflict LDS layout
__device__ __forceinline__ void kmap(int hidx, int& kh, int& slot) {
  kh = (hidx < 160) ? 0 : 1;
  slot = (hidx < 160) ? hidx : hidx - 160;
}

// ---------------------------------------------------------------------------
// LSTM (r11 structure; lines spread 256B apart across LLC banks/channels):
// 256 WGs = 32 groups x 8 chunks; group g = bid&31, chunk q = bid>>5.
// Lane: khalf=l&1, m=(l>>1)&3, octet o=l>>3. Wave: b=w&1, wh=w>>1.
// Thread = half a gate row (40 f4 in VGPR); shfl_xor(1)=k-reduce,
// shfl_xor(2,4)=gate butterfly; update redundant per octet; store lanes
// (l%24==0) pack 3 h/line into stamped 16B lines at 256B stride
// (dense 16B packing congests the serving LLC banks under ~1300
// simultaneous pollers/group — the suspected source of the 1.6us L).
// ---------------------------------------------------------------------------
__global__ __launch_bounds__(512, 1) void lstm_kernel(
    const float* __restrict__ actT,   // [B][E][T]
    const float* __restrict__ w_ih,   // [1024][64]
    const float* __restrict__ w_hh,   // [1024][256]
    const float* __restrict__ b_ih,
    const float* __restrict__ b_hh,
    float* hbuf,                      // [NG][2][NLINES][LSTRIDE] floats
    float* hfinal)                    // [NG][GB][H]
{
  __shared__ float sl[2][2][2][SLOT]; // [parity][batch][khalf][slot]

  const int bid = blockIdx.x;
  const int g = bid & 31;
  const int q = bid >> 5;
  const int tid = threadIdx.x;
  const int w = tid >> 6;
  const int l = tid & 63;

  const int khalf = l & 1;
  const int m     = (l >> 1) & 3;
  const int o     = l >> 3;                    // octet within wave
  const int b     = w & 1;
  const int wh    = w >> 1;
  const int hh    = wh*8 + o;                  // 0..31 within chunk
  const int row   = m*256 + 32*q + hh;         // gate row in [0,1024)

  // weights -> VGPRs: 40 f4 = half-row
  float4 wv[40];
  if (khalf == 0) {
    const float4* ph = (const float4*)(w_hh + (size_t)row*H_);
    #pragma unroll
    for (int i = 0; i < 40; ++i) wv[i] = ph[i];
  } else {
    const float4* ph = (const float4*)(w_hh + (size_t)row*H_) + 40;
    #pragma unroll
    for (int i = 0; i < 24; ++i) wv[i] = ph[i];
    const float4* px = (const float4*)(w_ih + (size_t)row*E_);
    #pragma unroll
    for (int i = 0; i < 16; ++i) wv[24+i] = px[i];
  }
  const float bias = (khalf == 0) ? (b_ih[row] + b_hh[row]) : 0.0f;

  // zero all LDS slices (t=0 parity-0 h = 0)
  for (int i = tid; i < 2*2*2*SLOT; i += 512) ((float*)sl)[i] = 0.0f;

  // ---- store-lane roles: l in {0,24,48}, slot ss=l/24
  const int ss = l / 24;
  const bool is_store = ((l % 24) == 0);
  const int sline = q*24 + w*3 + ss;
  const int shh0 = wh*8 + 3*ss;
  const int scnt = (ss == 2) ? 2 : 3;

  // ---- poller roles: non-store lanes of waves 0-2 (bijective rank 0..60)
  const bool lane_ok = ((l % 24) != 0);
  const int rank = l - 1 - (l >= 24) - (l >= 48);
  const int pi = w*61 + rank;
  const bool is_poll = (w < 3) && lane_ok && (pi < 168);
  int pline = 0, pb = 0, phh0 = 0, pcnt = 3;
  if (is_poll) {
    int qq = pi / 24;
    int pq = qq + (qq >= q ? 1 : 0);
    int rest = pi % 24;
    int pw = rest / 3, ps = rest % 3;
    pline = pq*24 + pw*3 + ps;
    pb = pw & 1;
    phh0 = 32*pq + (pw >> 1)*8 + 3*ps;
    pcnt = (ps == 2) ? 2 : 3;
  }

  // ---- x loader roles: tid in [384,512)
  const bool is_x = (tid >= 384);
  const int xi = tid - 384, xb = (xi >> 6) & 1, xe = xi & 63;
  const float* actp = actT + (size_t)((g*GB + xb)*E_ + xe)*T_;

  float* hb = hbuf + (size_t)g*(2*NLINES*LSTRIDE);   // floats

  // prologue: stage x(0)
  if (is_x) sl[0][xb][1][96 + xe] = actp[0];
  __syncthreads();

  float c = 0.0f;
  for (int t = 0; t < T_; ++t) {
    const int p = t & 1;

    float xval = 0.0f;
    if (is_x) xval = actp[t];

    // poll my remote line (frozen at stamp t until this WG passes barrier)
    if (t > 0 && is_poll) {
      const float* lp = hb + (size_t)(p*NLINES + pline)*LSTRIDE;
      f32x4 v = coh_load_f32x4(lp);
      while (__float_as_int(v[3]) != t) v = coh_load_f32x4(lp);
      #pragma unroll
      for (int j = 0; j < 3; ++j) {
        if (j < pcnt) {
          int kh, slot; kmap(phh0 + j, kh, slot);
          sl[p][pb][kh][slot] = v[j];
        }
      }
    }
    if (is_x) sl[p][xb][1][96 + xe] = xval;
    step_barrier();   // LDS drained; h/x ready (no vmcnt drain here)

    // half-row GEMV: 40 f4 broadcast LDS reads
    float acc = bias;
    {
      const float* hs = &sl[p][b][khalf][0];
      #pragma unroll
      for (int i = 0; i < 40; ++i) {
        float4 h4 = *(const float4*)(hs + i*4);
        acc += wv[i].x*h4.x + wv[i].y*h4.y + wv[i].z*h4.z + wv[i].w*h4.w;
      }
    }

    // k-half reduce + gate butterfly (lane bits: khalf=1, m=2|4)
    float ksum = acc + __shfl_xor(acc, 1);
    float x1 = __shfl_xor(ksum, 2);
    float x2 = __shfl_xor(ksum, 4);
    float x3 = __shfl_xor(x1, 4);
    float gi = (m==0)?ksum:(m==1)?x1 :(m==2)?x2 :x3;
    float gf = (m==0)?x1 :(m==1)?ksum:(m==2)?x3 :x2;
    float gg = (m==0)?x2 :(m==1)?x3 :(m==2)?ksum:x1;
    float go = (m==0)?x3 :(m==1)?x2 :(m==2)?x1 :ksum;

    float si = fast_sigmoid(gi);
    float sf = fast_sigmoid(gf);
    float so = fast_sigmoid(go);
    c = sf*c + si*fast_tanh(gg);
    float h = so*fast_tanh(c);

    // pack 3 octet-values into the store lane (wave-internal shfl)
    float v1 = __shfl(h, (l + 8) & 63, 64);
    float v2 = __shfl(h, (l + 16) & 63, 64);
    if (is_store) {
      f32x4 line;
      line[0] = h; line[1] = v1; line[2] = v2;
      line[3] = __int_as_float(t + 1);
      float* dp = hb + (size_t)((((t+1) & 1)*NLINES) + sline)*LSTRIDE;
      coh_store_f32x4(dp, line);
      // self-chunk bypass into next-parity LDS
      #pragma unroll
      for (int j = 0; j < 3; ++j) {
        if (j < scnt) {
          int kh, slot; kmap(32*q + shh0 + j, kh, slot);
          sl[p ^ 1][b][kh][slot] = (j == 0) ? h : (j == 1) ? v1 : v2;
        }
      }
      if (t == T_ - 1) {
        #pragma unroll
        for (int j = 0; j < 3; ++j)
          if (j < scnt)
            hfinal[(size_t)g*GB*H_ + (size_t)b*H_ + 32*q + shh0 + j]
                = (j == 0) ? h : (j == 1) ? v1 : v2;
      }
      // drain own stores only (store-data regs must not be reused earlier)
      asm volatile("s_waitcnt vmcnt(0)" ::: "memory");
    }
  }
}

// ---------------------------------------------------------------------------
// Head: out[b][o] = h_last[b] . lin_w[o] + lin_b[o]
// ---------------------------------------------------------------------------
__global__ void head_kernel(const float* __restrict__ hfinal,
                            const float* __restrict__ lw,
                            const float* __restrict__ lb,
                            float* __restrict__ out)
{
  int idx = blockIdx.x*blockDim.x + threadIdx.x;
  if (idx >= B_*OUT_) return;
  int b = idx / OUT_, o = idx % OUT_;
  int g = b >> 1, bl = b & 1;
  const float* h = hfinal + (size_t)g*GB*H_ + (size_t)bl*H_;
  const float* wv = lw + (size_t)o*H_;
  float s = lb[o];
  #pragma unroll 8
  for (int k = 0; k < H_; ++k) s += h[k]*wv[k];
  out[idx] = s;
}

extern "C" void kernel_launch(void* const* d_in, const int* in_sizes, int n_in,
                              void* d_out, int out_size, void* d_ws, size_t ws_size,
                              hipStream_t stream) {
  const float* inputs = (const float*)d_in[0];
  const float* conv_w = (const float*)d_in[3];
  const float* conv_b = (const float*)d_in[4];
  const float* w_ih   = (const float*)d_in[5];
  const float* w_hh   = (const float*)d_in[6];
  const float* b_ih   = (const float*)d_in[7];
  const float* b_hh   = (const float*)d_in[8];
  const float* lin_w  = (const float*)d_in[9];
  const float* lin_b  = (const float*)d_in[10];

  float* actT   = (float*)d_ws;
  float* hbuf   = (float*)((char*)d_ws + HBUF_OFF);
  float* hfinal = (float*)((char*)d_ws + HFINAL_OFF);

  // clear stamps each launch (graph-replay safe: stamps restart at 1)
  hipMemsetAsync(hbuf, 0, HBUF_BYTES, stream);
  hipLaunchKernelGGL(conv_kernel, dim3(B_*16), dim3(512), 192*128*4, stream,
                     inputs, conv_w, conv_b, actT);
  hipLaunchKernelGGL(lstm_kernel, dim3(NG*NCH), dim3(512), 0, stream,
                     actT, w_ih, w_hh, b_ih, b_hh, hbuf, hfinal);
  hipLaunchKernelGGL(head_kernel, dim3(3), dim3(256), 0, stream,
                     hfinal, lin_w, lin_b, (float*)d_out);
}

// Round 13
// 2124.917 us; speedup vs baseline: 1.1477x; 1.1477x over previous
//
#include <hip/hip_runtime.h>
#include <math.h>

#define B_   64
#define S_   3072
#define DIN  128
#define E_   64
#define H_   256
#define OUT_ 10
#define T_   1024
#define NG   32      // batch groups (2 batches each)
#define GB   2
#define NCH  8       // chunk-WGs per group; WG q owns h-indices [32q,32q+32)
#define NLINES 192   // stamped lines per group per parity: [q][wave][s] 8*8*3

// workspace layout (bytes)
#define ACT_BYTES   (B_*E_*T_*4)              // actT[b][e][t] fp32 = 16 MB
#define HBUF_OFF    ACT_BYTES
#define HBUF_BYTES  (NG*2*NLINES*16)          // 192 KB, dense (r12: spreading hurt)
#define HFINAL_OFF  (HBUF_OFF + HBUF_BYTES)
#define HFINAL_BYTES (NG*GB*H_*4)             // 64 KB

typedef float f32x4 __attribute__((ext_vector_type(4)));

// IF-coherent access (cross-XCD safe, fence-free). Proven rounds 2/4/6/7/11.
// NOTE: sc0-only ("XCD-local") exchange hangs — twice confirmed (r3, r10).
__device__ __forceinline__ f32x4 coh_load_f32x4(const float* p) {
  f32x4 r;
  asm volatile("global_load_dwordx4 %0, %1, off sc0 sc1\n\ts_waitcnt vmcnt(0)"
               : "=v"(r) : "v"(p) : "memory");
  return r;
}
__device__ __forceinline__ void coh_store_f32x4(float* p, f32x4 v) {
  asm volatile("global_store_dwordx4 %0, %1, off sc0 sc1" :: "v"(p), "v"(v) : "memory");
}

// step barrier: LDS-drain only (store lanes self-drain their own vmcnt)
__device__ __forceinline__ void step_barrier() {
  asm volatile("s_waitcnt lgkmcnt(0)" ::: "memory");
  __builtin_amdgcn_sched_barrier(0);
  __builtin_amdgcn_s_barrier();
}

__device__ __forceinline__ float fast_sigmoid(float x) {
  return __builtin_amdgcn_rcpf(1.0f + __expf(-x));
}
__device__ __forceinline__ float fast_tanh(float x) {
  return 2.0f * __builtin_amdgcn_rcpf(1.0f + __expf(-2.0f * x)) - 1.0f;
}

// ---------------------------------------------------------------------------
// Conv: normalize rows (L2 over D=128), conv1d k=3 stride=3, +bias, relu.
// ---------------------------------------------------------------------------
__global__ __launch_bounds__(512, 1) void conv_kernel(
    const float* __restrict__ in,     // [B][S][DIN]
    const float* __restrict__ cw,     // [E][DIN][3]
    const float* __restrict__ cb,     // [E]
    float* __restrict__ actT)         // [B][E][T]
{
  extern __shared__ float xs[];                 // 192 rows x 128 f, swizzled
  float4* xs4 = (float4*)xs;
  const int bid = blockIdx.x;
  const int b  = bid >> 4;
  const int tb = bid & 15;
  const int tid = threadIdx.x;

  const float4* gin = (const float4*)(in + (size_t)b*S_*DIN + (size_t)tb*192*DIN);
  #pragma unroll
  for (int i = 0; i < 12; ++i) {
    int f4 = tid + i*512;
    int r = f4 >> 5, dq = f4 & 31;
    xs4[r*32 + (dq ^ (r & 7))] = gin[f4];
  }
  __syncthreads();

  const int wv = tid >> 6, ln = tid & 63;
  for (int rr = 0; rr < 24; ++rr) {
    int r = wv*24 + rr;
    int u = r*32 + ((ln >> 1) ^ (r & 7));
    float2* p = (float2*)((char*)xs + (size_t)u*16 + (size_t)(ln & 1)*8);
    float2 v = *p;
    float s = v.x*v.x + v.y*v.y;
    #pragma unroll
    for (int off = 32; off >= 1; off >>= 1) s += __shfl_xor(s, off);
    float inv = 1.0f / fmaxf(sqrtf(s), 1e-12f);
    v.x *= inv; v.y *= inv;
    *p = v;
  }
  __syncthreads();

  const int eo = __builtin_amdgcn_readfirstlane(wv);
  float acc[8];
  #pragma unroll
  for (int j = 0; j < 8; ++j) acc[j] = cb[eo*8 + j];

  const int r0 = 3*ln, r1 = 3*ln + 1, r2 = 3*ln + 2;
  #pragma unroll 4
  for (int dq = 0; dq < 32; ++dq) {
    float4 x0 = xs4[r0*32 + (dq ^ (r0 & 7))];
    float4 x1 = xs4[r1*32 + (dq ^ (r1 & 7))];
    float4 x2 = xs4[r2*32 + (dq ^ (r2 & 7))];
    #pragma unroll
    for (int j = 0; j < 8; ++j) {
      const float* wp = cw + (size_t)(eo*8 + j)*(DIN*3) + dq*12;  // uniform
      acc[j] += x0.x*wp[0] + x1.x*wp[1] + x2.x*wp[2]
              + x0.y*wp[3] + x1.y*wp[4] + x2.y*wp[5]
              + x0.z*wp[6] + x1.z*wp[7] + x2.z*wp[8]
              + x0.w*wp[9] + x1.w*wp[10] + x2.w*wp[11];
    }
  }

  const int tg = tb*64 + ln;
  #pragma unroll
  for (int j = 0; j < 8; ++j) {
    int e = eo*8 + j;
    actT[(size_t)b*E_*T_ + (size_t)e*T_ + tg] = fmaxf(acc[j], 0.0f);
  }
}

// ---------------------------------------------------------------------------
// LSTM (r11 structure + 3-deep staggered poll + pre-barrier x-GEMV):
// 256 WGs = 32 groups x 8 chunks; group g = bid&31, chunk q = bid>>5.
// Lane: khalf=l&1, m=(l>>1)&3, octet o=l>>3. Wave: b=w&1, wh=w>>1.
// Thread = half a gate row: w_hh k-half (32 f4, post-barrier) + w_ih half
// (8 f4, PRE-barrier — x(t) double-buffered in LDS one step ahead).
// Poll: 3 outstanding sc0sc1 loads, s_waitcnt vmcnt(2) waits oldest only,
// s_sleep(4) spacing -> sampling ~4x faster than one RT; sched_barrier(0)
// after each counted wait (rule: hipcc hoists reg-only ops past asm waits).
// Poller lanes have no other VMEM in flight (store lanes/x-loaders disjoint).
// ---------------------------------------------------------------------------
__global__ __launch_bounds__(512, 1) void lstm_kernel(
    const float* __restrict__ actT,   // [B][E][T]
    const float* __restrict__ w_ih,   // [1024][64]
    const float* __restrict__ w_hh,   // [1024][256]
    const float* __restrict__ b_ih,
    const float* __restrict__ b_hh,
    float* hbuf,                      // [NG][2][NLINES] f32x4 lines
    float* hfinal)                    // [NG][GB][H]
{
  __shared__ float hl[2][2][2][132];  // [parity][batch][khalf][128 + pad]
  __shared__ float xl[2][2][64];      // [parity][batch][e]

  const int bid = blockIdx.x;
  const int g = bid & 31;
  const int q = bid >> 5;
  const int tid = threadIdx.x;
  const int w = tid >> 6;
  const int l = tid & 63;

  const int khalf = l & 1;
  const int m     = (l >> 1) & 3;
  const int o     = l >> 3;                    // octet within wave
  const int b     = w & 1;
  const int wh    = w >> 1;
  const int hh    = wh*8 + o;                  // 0..31 within chunk
  const int row   = m*256 + 32*q + hh;         // gate row in [0,1024)

  // weights -> VGPRs: 32 f4 of w_hh (k-half) + 8 f4 of w_ih (x-half)
  float4 wv[40];
  {
    const float4* ph = (const float4*)(w_hh + (size_t)row*H_) + khalf*32;
    #pragma unroll
    for (int i = 0; i < 32; ++i) wv[i] = ph[i];
    const float4* px = (const float4*)(w_ih + (size_t)row*E_) + khalf*8;
    #pragma unroll
    for (int i = 0; i < 8; ++i) wv[32+i] = px[i];
  }
  const float bias = (khalf == 0) ? (b_ih[row] + b_hh[row]) : 0.0f;

  // zero h LDS (t=0 parity-0 h = 0)
  for (int i = tid; i < 2*2*2*132; i += 512) (&hl[0][0][0][0])[i] = 0.0f;

  // ---- store-lane roles: l in {0,24,48}, slot ss=l/24
  const int ss = l / 24;
  const bool is_store = ((l % 24) == 0);
  const int sline = q*24 + w*3 + ss;
  const int shh0 = wh*8 + 3*ss;
  const int scnt = (ss == 2) ? 2 : 3;

  // ---- poller roles: non-store lanes of waves 0-2 (bijective rank 0..60)
  const bool lane_ok = ((l % 24) != 0);
  const int rank = l - 1 - (l >= 24) - (l >= 48);
  const int pi = w*61 + rank;
  const bool is_poll = (w < 3) && lane_ok && (pi < 168);
  int pline = 0, pb = 0, phh0 = 0, pcnt = 3;
  if (is_poll) {
    int qq = pi / 24;
    int pq = qq + (qq >= q ? 1 : 0);
    int rest = pi % 24;
    int pw = rest / 3, ps = rest % 3;
    pline = pq*24 + pw*3 + ps;
    pb = pw & 1;
    phh0 = 32*pq + (pw >> 1)*8 + 3*ps;
    pcnt = (ps == 2) ? 2 : 3;
  }

  // ---- x loader roles: tid in [384,512) stage x one step AHEAD
  const bool is_x = (tid >= 384);
  const int xi = tid - 384, xb = (xi >> 6) & 1, xe = xi & 63;
  const float* actp = actT + (size_t)((g*GB + xb)*E_ + xe)*T_;

  float* hb = hbuf + (size_t)g*(2*NLINES*4);   // floats

  // prologue: stage x(0) into xl[0]
  if (is_x) xl[0][xb][xe] = actp[0];
  __syncthreads();

  float c = 0.0f;
  for (int t = 0; t < T_; ++t) {
    const int p = t & 1;

    // ---- pre-barrier: x-part GEMV (x(t) staged last iter, synced)
    float acc = bias;
    {
      const float* xp = &xl[p][b][khalf*32];
      #pragma unroll
      for (int i = 0; i < 8; ++i) {
        float4 x4 = *(const float4*)(xp + 4*i);
        acc += wv[32+i].x*x4.x + wv[32+i].y*x4.y
             + wv[32+i].z*x4.z + wv[32+i].w*x4.w;
      }
    }
    // stage x(t+1)
    if (is_x) {
      float xv = actp[(t + 1 < T_) ? (t + 1) : t];
      xl[p ^ 1][xb][xe] = xv;
    }

    // ---- 3-deep staggered poll (counted vmcnt; no other VMEM in pollers)
    if (t > 0 && is_poll) {
      const float* lp = hb + (size_t)(p*NLINES + pline)*4;
      f32x4 va, vb, vc, hit = {};
      asm volatile("global_load_dwordx4 %0, %1, off sc0 sc1" : "=v"(va) : "v"(lp) : "memory");
      __builtin_amdgcn_s_sleep(4);
      asm volatile("global_load_dwordx4 %0, %1, off sc0 sc1" : "=v"(vb) : "v"(lp) : "memory");
      __builtin_amdgcn_s_sleep(4);
      asm volatile("global_load_dwordx4 %0, %1, off sc0 sc1" : "=v"(vc) : "v"(lp) : "memory");
      for (;;) {
        asm volatile("s_waitcnt vmcnt(2)" ::: "memory");
        __builtin_amdgcn_sched_barrier(0);
        if (__float_as_int(va[3]) == t) { hit = va; break; }
        asm volatile("global_load_dwordx4 %0, %1, off sc0 sc1" : "=v"(va) : "v"(lp) : "memory");
        __builtin_amdgcn_s_sleep(4);
        asm volatile("s_waitcnt vmcnt(2)" ::: "memory");
        __builtin_amdgcn_sched_barrier(0);
        if (__float_as_int(vb[3]) == t) { hit = vb; break; }
        asm volatile("global_load_dwordx4 %0, %1, off sc0 sc1" : "=v"(vb) : "v"(lp) : "memory");
        __builtin_amdgcn_s_sleep(4);
        asm volatile("s_waitcnt vmcnt(2)" ::: "memory");
        __builtin_amdgcn_sched_barrier(0);
        if (__float_as_int(vc[3]) == t) { hit = vc; break; }
        asm volatile("global_load_dwordx4 %0, %1, off sc0 sc1" : "=v"(vc) : "v"(lp) : "memory");
        __builtin_amdgcn_s_sleep(4);
      }
      asm volatile("s_waitcnt vmcnt(0)" ::: "memory");  // drain stale polls
      __builtin_amdgcn_sched_barrier(0);
      #pragma unroll
      for (int j = 0; j < 3; ++j) {
        if (j < pcnt) {
          int hidx = phh0 + j;
          hl[p][pb][hidx >> 7][hidx & 127] = hit[j];
        }
      }
    }
    step_barrier();   // LDS drained; h/x ready (no vmcnt drain here)

    // ---- post-barrier: h-part GEMV (32 f4)
    {
      const float* hs = &hl[p][b][khalf][0];
      #pragma unroll
      for (int i = 0; i < 32; ++i) {
        float4 h4 = *(const float4*)(hs + 4*i);
        acc += wv[i].x*h4.x + wv[i].y*h4.y + wv[i].z*h4.z + wv[i].w*h4.w;
      }
    }

    // k-half reduce + gate butterfly (lane bits: khalf=1, m=2|4)
    float ksum = acc + __shfl_xor(acc, 1);
    float x1 = __shfl_xor(ksum, 2);
    float x2 = __shfl_xor(ksum, 4);
    float x3 = __shfl_xor(x1, 4);
    float gi = (m==0)?ksum:(m==1)?x1 :(m==2)?x2 :x3;
    float gf = (m==0)?x1 :(m==1)?ksum:(m==2)?x3 :x2;
    float gg = (m==0)?x2 :(m==1)?x3 :(m==2)?ksum:x1;
    float go = (m==0)?x3 :(m==1)?x2 :(m==2)?x1 :ksum;

    float si = fast_sigmoid(gi);
    float sf = fast_sigmoid(gf);
    float so = fast_sigmoid(go);
    c = sf*c + si*fast_tanh(gg);
    float h = so*fast_tanh(c);

    // pack 3 octet-values into the store lane (wave-internal shfl)
    float v1 = __shfl(h, (l + 8) & 63, 64);
    float v2 = __shfl(h, (l + 16) & 63, 64);
    if (is_store) {
      f32x4 line;
      line[0] = h; line[1] = v1; line[2] = v2;
      line[3] = __int_as_float(t + 1);
      float* dp = hb + (size_t)((((t+1) & 1)*NLINES) + sline)*4;
      coh_store_f32x4(dp, line);
      // self-chunk bypass into next-parity LDS
      #pragma unroll
      for (int j = 0; j < 3; ++j) {
        if (j < scnt) {
          int hidx = 32*q + shh0 + j;
          hl[p ^ 1][b][hidx >> 7][hidx & 127] = (j == 0) ? h : (j == 1) ? v1 : v2;
        }
      }
      if (t == T_ - 1) {
        #pragma unroll
        for (int j = 0; j < 3; ++j)
          if (j < scnt)
            hfinal[(size_t)g*GB*H_ + (size_t)b*H_ + 32*q + shh0 + j]
                = (j == 0) ? h : (j == 1) ? v1 : v2;
      }
      // drain own stores only (store-data regs must not be reused earlier)
      asm volatile("s_waitcnt vmcnt(0)" ::: "memory");
    }
  }
}

// ---------------------------------------------------------------------------
// Head: out[b][o] = h_last[b] . lin_w[o] + lin_b[o]
// ---------------------------------------------------------------------------
__global__ void head_kernel(const float* __restrict__ hfinal,
                            const float* __restrict__ lw,
                            const float* __restrict__ lb,
                            float* __restrict__ out)
{
  int idx = blockIdx.x*blockDim.x + threadIdx.x;
  if (idx >= B_*OUT_) return;
  int b = idx / OUT_, o = idx % OUT_;
  int g = b >> 1, bl = b & 1;
  const float* h = hfinal + (size_t)g*GB*H_ + (size_t)bl*H_;
  const float* wv = lw + (size_t)o*H_;
  float s = lb[o];
  #pragma unroll 8
  for (int k = 0; k < H_; ++k) s += h[k]*wv[k];
  out[idx] = s;
}

extern "C" void kernel_launch(void* const* d_in, const int* in_sizes, int n_in,
                              void* d_out, int out_size, void* d_ws, size_t ws_size,
                              hipStream_t stream) {
  const float* inputs = (const float*)d_in[0];
  const float* conv_w = (const float*)d_in[3];
  const float* conv_b = (const float*)d_in[4];
  const float* w_ih   = (const float*)d_in[5];
  const float* w_hh   = (const float*)d_in[6];
  const float* b_ih   = (const float*)d_in[7];
  const float* b_hh   = (const float*)d_in[8];
  const float* lin_w  = (const float*)d_in[9];
  const float* lin_b  = (const float*)d_in[10];

  float* actT   = (float*)d_ws;
  float* hbuf   = (float*)((char*)d_ws + HBUF_OFF);
  float* hfinal = (float*)((char*)d_ws + HFINAL_OFF);

  // clear stamps each launch (graph-replay safe: stamps restart at 1)
  hipMemsetAsync(hbuf, 0, HBUF_BYTES, stream);
  hipLaunchKernelGGL(conv_kernel, dim3(B_*16), dim3(512), 192*128*4, stream,
                     inputs, conv_w, conv_b, actT);
  hipLaunchKernelGGL(lstm_kernel, dim3(NG*NCH), dim3(512), 0, stream,
                     actT, w_ih, w_hh, b_ih, b_hh, hbuf, hfinal);
  hipLaunchKernelGGL(head_kernel, dim3(3), dim3(256), 0, stream,
                     hfinal, lin_w, lin_b, (float*)d_out);
}